// Round 3
// baseline (743.763 us; speedup 1.0000x reference)
//
#include <hip/hip_runtime.h>
#include <hip/hip_bf16.h>

// Problem constants
constexpr int Bn = 8, Sn = 2048, En = 512, Hn = 4, Dn = 128;
constexpr int BHn = Bn * Hn;          // 32
constexpr int Mqkv = Bn * Sn;         // 16384

typedef __attribute__((ext_vector_type(8))) short short8;
typedef __attribute__((ext_vector_type(4))) float f32x4;

__device__ __forceinline__ unsigned short f2bf(float f) {
  unsigned int u = __builtin_bit_cast(unsigned int, f);
  u += 0x7FFF + ((u >> 16) & 1);   // round-to-nearest-even
  return (unsigned short)(u >> 16);
}

// raw barrier: publish LDS writes (lgkmcnt(0)) but do NOT drain vmcnt,
// so register-prefetch global loads stay in flight across the barrier.
__device__ __forceinline__ void bar_pub() {
  asm volatile("s_waitcnt lgkmcnt(0)" ::: "memory");
  __builtin_amdgcn_s_barrier();
  asm volatile("" ::: "memory");
}

// ---------------------------------------------------------------------------
// K1: QKV projection (unchanged from R2).
// ---------------------------------------------------------------------------
__global__ __launch_bounds__(256) void qkv_kernel(
    const float* __restrict__ x, const float* __restrict__ Wq,
    const float* __restrict__ Wk, const float* __restrict__ Wv,
    const float* __restrict__ bq, const float* __restrict__ bk,
    const float* __restrict__ bv, unsigned short* __restrict__ qkv) {
  const int z = blockIdx.z;
  const float* W = (z == 0) ? Wq : (z == 1 ? Wk : Wv);
  const float* bias = (z == 0) ? bq : (z == 1 ? bk : bv);
  unsigned short* out = qkv + (size_t)z * BHn * Sn * Dn;

  __shared__ unsigned short As[128][40];
  __shared__ unsigned short BsT[128][40];

  const int t = threadIdx.x;
  const int l = t & 63, w = t >> 6;
  const int wm = w >> 1, wn = w & 1;
  const int m0 = blockIdx.x * 128, n0 = blockIdx.y * 128;

  f32x4 acc[4][4] = {};

  for (int k0 = 0; k0 < En; k0 += 32) {
    __syncthreads();
#pragma unroll
    for (int i = 0; i < 4; ++i) {
      int idx = t + i * 256;
      int row = idx >> 3, c4 = (idx & 7) * 4;
      float4 v = *reinterpret_cast<const float4*>(&x[(size_t)(m0 + row) * En + k0 + c4]);
      ushort4 p;
      p.x = f2bf(v.x); p.y = f2bf(v.y); p.z = f2bf(v.z); p.w = f2bf(v.w);
      *reinterpret_cast<ushort4*>(&As[row][c4]) = p;
    }
#pragma unroll
    for (int i = 0; i < 4; ++i) {
      int idx = t + i * 256;
      int kk = idx >> 5, c4 = (idx & 31) * 4;
      float4 v = *reinterpret_cast<const float4*>(&W[(size_t)(k0 + kk) * En + n0 + c4]);
      BsT[c4 + 0][kk] = f2bf(v.x);
      BsT[c4 + 1][kk] = f2bf(v.y);
      BsT[c4 + 2][kk] = f2bf(v.z);
      BsT[c4 + 3][kk] = f2bf(v.w);
    }
    __syncthreads();

    const int koff = (l >> 4) * 8;
    short8 a[4], bfr[4];
#pragma unroll
    for (int m = 0; m < 4; ++m)
      a[m] = *reinterpret_cast<const short8*>(&As[wm * 64 + m * 16 + (l & 15)][koff]);
#pragma unroll
    for (int n = 0; n < 4; ++n)
      bfr[n] = *reinterpret_cast<const short8*>(&BsT[wn * 64 + n * 16 + (l & 15)][koff]);
#pragma unroll
    for (int m = 0; m < 4; ++m)
#pragma unroll
      for (int n = 0; n < 4; ++n)
        acc[m][n] = __builtin_amdgcn_mfma_f32_16x16x32_bf16(a[m], bfr[n], acc[m][n], 0, 0, 0);
  }

#pragma unroll
  for (int m = 0; m < 4; ++m)
#pragma unroll
    for (int n = 0; n < 4; ++n)
#pragma unroll
      for (int j = 0; j < 4; ++j) {
        int row = m0 + wm * 64 + m * 16 + (l >> 4) * 4 + j;
        int col = n0 + wn * 64 + n * 16 + (l & 15);
        int s = row & (Sn - 1);
        float v = acc[m][n][j] + bias[s];
        int b = row >> 11;
        int h = col >> 7, d = col & 127;
        out[(size_t)((b * Hn + h) * Sn + s) * Dn + d] = f2bf(v);
      }
}

// ---------------------------------------------------------------------------
// K1b: V transpose  v[bh][s][d] -> vT[bh][d][s].  64x64 tiles through LDS.
// ---------------------------------------------------------------------------
__global__ __launch_bounds__(256) void vtrans_kernel(
    const unsigned short* __restrict__ v, unsigned short* __restrict__ vT) {
  const int s0 = blockIdx.x * 64, d0 = blockIdx.y * 64;
  const int bh = blockIdx.z;
  const unsigned short* vp = v + (size_t)bh * Sn * Dn;
  unsigned short* op = vT + (size_t)bh * Dn * Sn;
  __shared__ unsigned short Ls[64][72];
  const int t = threadIdx.x;
#pragma unroll
  for (int it = 0; it < 2; ++it) {
    int flat = t + it * 256;
    int r = flat >> 3, cc = flat & 7;
    *reinterpret_cast<short8*>(&Ls[r][cc * 8]) =
        *reinterpret_cast<const short8*>(&vp[(size_t)(s0 + r) * Dn + d0 + cc * 8]);
  }
  __syncthreads();
#pragma unroll
  for (int it = 0; it < 2; ++it) {
    int flat = t + it * 256;
    int d = flat >> 3, sc = flat & 7;
    short8 o;
#pragma unroll
    for (int jo = 0; jo < 8; ++jo) {
      int jj = (jo + sc) & 7;   // rotation -> conflict-free column reads
      o[jj] = (short)Ls[sc * 8 + jj][d];
    }
    *reinterpret_cast<short8*>(&op[(size_t)(d0 + d) * Sn + s0 + sc * 8]) = o;
  }
}

// ---------------------------------------------------------------------------
// K2: fused scores+softmax+mask+attn-write+PV, v2.
// Block = 64 q-rows of one (b,h); grid (32, 32); 256 thr (4 waves).
// QK^T: wave w -> cols w*16+i (KVBLK=64, 32 tiles).  Q in registers.
// K double-buffered LDS + register prefetch; raw barriers (no vmcnt drain).
// Sweep1: per-lane exp-sums (reduce ONCE at end).  Sweep2: recompute,
// p=exp*invl*Wepi -> attn f32 (only write), bf16 Ps -> PV MFMA (V^T tiles).
// ---------------------------------------------------------------------------
__global__ __launch_bounds__(256, 2) void fused_attn2_kernel(
    const unsigned short* __restrict__ qkv, const unsigned short* __restrict__ vT,
    const float* __restrict__ Wepi, const float* __restrict__ bo,
    float* __restrict__ attn, float* __restrict__ effect) {
  const int bh = blockIdx.y;
  const int s0 = blockIdx.x * 64;
  const unsigned short* qp = qkv + (size_t)bh * Sn * Dn;
  const unsigned short* kp = qkv + (size_t)(BHn + bh) * Sn * Dn;
  const unsigned short* vt = vT + (size_t)bh * Dn * Sn;

  __shared__ unsigned short Kb[2][64 * 128];   // XOR-swizzled 16B chunks
  __shared__ unsigned short Vt[128 * 64];      // [d][t], XOR-swizzled
  __shared__ unsigned short Ps[64 * 64];       // [s][t], XOR-swizzled
  __shared__ float wpart[4][64];
  __shared__ float invl[64];

  const int t = threadIdx.x, l = t & 63, w = t >> 6;
  const int g = l >> 4, i = l & 15;
  const float scale = 0.022097086912079608f;  // 1/sqrt(2048)

  // Q fragments resident in registers: aq[mf][ks]
  short8 aq[4][4];
#pragma unroll
  for (int mf = 0; mf < 4; ++mf)
#pragma unroll
    for (int ks = 0; ks < 4; ++ks)
      aq[mf][ks] = *reinterpret_cast<const short8*>(
          &qp[(size_t)(s0 + mf * 16 + i) * Dn + ks * 32 + g * 8]);

  // staging descriptors (per-thread)
  int ksrc[4], kdst[4], vsrc[4], vdst[4];
#pragma unroll
  for (int it = 0; it < 4; ++it) {
    int flat = t + it * 256;
    int r = flat >> 4, cc = flat & 15;           // K tile: 64 rows x 16 chunks
    ksrc[it] = r * Dn + cc * 8;
    kdst[it] = r * 128 + ((cc ^ (r & 15)) << 3);
    int d = flat >> 3, ct = flat & 7;            // Vt tile: 128 rows x 8 chunks
    vsrc[it] = d * Sn + ct * 8;
    vdst[it] = d * 64 + ((ct ^ (d & 7)) << 3);
  }

  // ---------------- sweep 1: exp row-sums ----------------
  short8 kreg[4];
#pragma unroll
  for (int it = 0; it < 4; ++it)
    kreg[it] = *reinterpret_cast<const short8*>(&kp[ksrc[it]]);
#pragma unroll
  for (int it = 0; it < 4; ++it)
    *reinterpret_cast<short8*>(&Kb[0][kdst[it]]) = kreg[it];
#pragma unroll
  for (int it = 0; it < 4; ++it)
    kreg[it] = *reinterpret_cast<const short8*>(&kp[(size_t)64 * Dn + ksrc[it]]);
  bar_pub();

  float rs[4][4];
#pragma unroll
  for (int mf = 0; mf < 4; ++mf)
#pragma unroll
    for (int j = 0; j < 4; ++j) rs[mf][j] = 0.f;

  for (int kt = 0; kt < 32; ++kt) {
    const int b = kt & 1;
    f32x4 acc[4] = {};
#pragma unroll
    for (int ks = 0; ks < 4; ++ks) {
      short8 bk = *reinterpret_cast<const short8*>(
          &Kb[b][(w * 16 + i) * 128 + (((ks * 4 + g) ^ i) << 3)]);
#pragma unroll
      for (int mf = 0; mf < 4; ++mf)
        acc[mf] = __builtin_amdgcn_mfma_f32_16x16x32_bf16(aq[mf][ks], bk, acc[mf], 0, 0, 0);
    }
#pragma unroll
    for (int mf = 0; mf < 4; ++mf)
#pragma unroll
      for (int j = 0; j < 4; ++j)
        rs[mf][j] += __expf(acc[mf][j] * scale);   // per-lane partial, no shuffles
    if (kt < 31) {
#pragma unroll
      for (int it = 0; it < 4; ++it)
        *reinterpret_cast<short8*>(&Kb[b ^ 1][kdst[it]]) = kreg[it];
      if (kt < 30)
#pragma unroll
        for (int it = 0; it < 4; ++it)
          kreg[it] = *reinterpret_cast<const short8*>(
              &kp[(size_t)(kt + 2) * 64 * Dn + ksrc[it]]);
    }
    bar_pub();
  }

  // single cross-lane reduce over the 16 i-lanes
#pragma unroll
  for (int mf = 0; mf < 4; ++mf)
#pragma unroll
    for (int j = 0; j < 4; ++j) {
      float s = rs[mf][j];
      s += __shfl_xor(s, 1); s += __shfl_xor(s, 2);
      s += __shfl_xor(s, 4); s += __shfl_xor(s, 8);
      if (i == 0) wpart[w][mf * 16 + g * 4 + j] = s;
    }
  bar_pub();
  if (t < 64) invl[t] = 1.0f / (wpart[0][t] + wpart[1][t] + wpart[2][t] + wpart[3][t]);
  bar_pub();
  float rinv[4][4];
#pragma unroll
  for (int mf = 0; mf < 4; ++mf)
#pragma unroll
    for (int j = 0; j < 4; ++j) rinv[mf][j] = invl[mf * 16 + g * 4 + j];

  // ---------------- sweep 2: recompute, write attn, PV ----------------
  short8 vreg[4];
#pragma unroll
  for (int it = 0; it < 4; ++it) {
    kreg[it] = *reinterpret_cast<const short8*>(&kp[ksrc[it]]);
    vreg[it] = *reinterpret_cast<const short8*>(&vt[vsrc[it]]);
  }
#pragma unroll
  for (int it = 0; it < 4; ++it) {
    *reinterpret_cast<short8*>(&Kb[0][kdst[it]]) = kreg[it];
    *reinterpret_cast<short8*>(&Vt[vdst[it]]) = vreg[it];
  }
#pragma unroll
  for (int it = 0; it < 4; ++it) {
    kreg[it] = *reinterpret_cast<const short8*>(&kp[(size_t)64 * Dn + ksrc[it]]);
    vreg[it] = *reinterpret_cast<const short8*>(&vt[64 + vsrc[it]]);
  }
  bar_pub();

  f32x4 pv[4][2] = {};
  float* attn_bh = attn + (size_t)bh * Sn * Sn;

  for (int kt = 0; kt < 32; ++kt) {
    const int b = kt & 1;
    const int t0 = kt * 64;
    f32x4 acc[4] = {};
#pragma unroll
    for (int ks = 0; ks < 4; ++ks) {
      short8 bk = *reinterpret_cast<const short8*>(
          &Kb[b][(w * 16 + i) * 128 + (((ks * 4 + g) ^ i) << 3)]);
#pragma unroll
      for (int mf = 0; mf < 4; ++mf)
        acc[mf] = __builtin_amdgcn_mfma_f32_16x16x32_bf16(aq[mf][ks], bk, acc[mf], 0, 0, 0);
    }
    // epilogue: p = exp*invl*Wepi -> global attn (f32, the only write) + Ps
#pragma unroll
    for (int mf = 0; mf < 4; ++mf)
#pragma unroll
      for (int j = 0; j < 4; ++j) {
        const int row = mf * 16 + g * 4 + j;
        const int col = w * 16 + i;
        float p = __expf(acc[mf][j] * scale) * rinv[mf][j];
        float pf = p * Wepi[(size_t)(s0 + row) * Sn + t0 + col];
        attn_bh[(size_t)(s0 + row) * Sn + t0 + col] = pf;
        Ps[row * 64 + ((((col >> 3) ^ (row & 7)) << 3) | (col & 7))] = f2bf(pf);
      }
    if (kt < 31)
#pragma unroll
      for (int it = 0; it < 4; ++it)
        *reinterpret_cast<short8*>(&Kb[b ^ 1][kdst[it]]) = kreg[it];
    bar_pub();   // Ps + next-K visible

    // PV accumulate: Ps [64s x 64t]  x  Vt [128d x 64t]
#pragma unroll
    for (int ks = 0; ks < 2; ++ks) {
      short8 pa[4], bv[2];
#pragma unroll
      for (int mf = 0; mf < 4; ++mf)
        pa[mf] = *reinterpret_cast<const short8*>(
            &Ps[(mf * 16 + i) * 64 + (((ks * 4 + g) ^ (i & 7)) << 3)]);
#pragma unroll
      for (int nf = 0; nf < 2; ++nf) {
        const int d = w * 32 + nf * 16 + i;
        bv[nf] = *reinterpret_cast<const short8*>(
            &Vt[d * 64 + (((ks * 4 + g) ^ (d & 7)) << 3)]);
      }
#pragma unroll
      for (int mf = 0; mf < 4; ++mf)
#pragma unroll
        for (int nf = 0; nf < 2; ++nf)
          pv[mf][nf] = __builtin_amdgcn_mfma_f32_16x16x32_bf16(pa[mf], bv[nf], pv[mf][nf], 0, 0, 0);
    }
    bar_pub();   // Vt/Ps reads done

    if (kt < 31) {
#pragma unroll
      for (int it = 0; it < 4; ++it)
        *reinterpret_cast<short8*>(&Vt[vdst[it]]) = vreg[it];
      if (kt < 30) {
#pragma unroll
        for (int it = 0; it < 4; ++it) {
          kreg[it] = *reinterpret_cast<const short8*>(
              &kp[(size_t)(t0 + 128) * Dn + ksrc[it]]);
          vreg[it] = *reinterpret_cast<const short8*>(&vt[t0 + 128 + vsrc[it]]);
        }
      }
    }
  }

  // effect = pv + bo
  const int b_ = bh >> 2, h_ = bh & 3;
#pragma unroll
  for (int mf = 0; mf < 4; ++mf)
#pragma unroll
    for (int j = 0; j < 4; ++j) {
      const int row = mf * 16 + g * 4 + j;
      const float bias = bo[s0 + row];
#pragma unroll
      for (int nf = 0; nf < 2; ++nf) {
        const int d = w * 32 + nf * 16 + i;
        effect[(size_t)(b_ * Sn + s0 + row) * En + h_ * Dn + d] = pv[mf][nf][j] + bias;
      }
    }
}

// ---------------------------------------------------------------------------
extern "C" void kernel_launch(void* const* d_in, const int* in_sizes, int n_in,
                              void* d_out, int out_size, void* d_ws, size_t ws_size,
                              hipStream_t stream) {
  const float* x    = (const float*)d_in[0];
  const float* Wq   = (const float*)d_in[1];
  const float* Wk   = (const float*)d_in[2];
  const float* Wv   = (const float*)d_in[3];
  const float* Wepi = (const float*)d_in[4];
  const float* bq   = (const float*)d_in[5];
  const float* bk   = (const float*)d_in[6];
  const float* bv   = (const float*)d_in[7];
  const float* bo   = (const float*)d_in[8];

  float* effect = (float*)d_out;
  float* attn = effect + (size_t)Bn * Sn * En;              // attn region of d_out
  unsigned short* qkv = (unsigned short*)d_ws;              // q|k|v bf16 (50.3 MB)
  unsigned short* vT = qkv + (size_t)3 * BHn * Sn * Dn;     // v^T bf16 (16.8 MB)

  qkv_kernel<<<dim3(Mqkv / 128, En / 128, 3), 256, 0, stream>>>(x, Wq, Wk, Wv, bq, bk, bv, qkv);
  vtrans_kernel<<<dim3(Sn / 64, Dn / 64, BHn), 256, 0, stream>>>(
      qkv + (size_t)2 * BHn * Sn * Dn, vT);
  fused_attn2_kernel<<<dim3(Sn / 64, BHn), 256, 0, stream>>>(qkv, vT, Wepi, bo, attn, effect);
}

// Round 4
// 398.377 us; speedup vs baseline: 1.8670x; 1.8670x over previous
//
#include <hip/hip_runtime.h>
#include <hip/hip_bf16.h>

// Problem constants
constexpr int Bn = 8, Sn = 2048, En = 512, Hn = 4, Dn = 128;
constexpr int BHn = Bn * Hn;          // 32
constexpr int Mqkv = Bn * Sn;         // 16384

typedef __attribute__((ext_vector_type(8))) short short8;
typedef __attribute__((ext_vector_type(4))) float f32x4;

__device__ __forceinline__ unsigned short f2bf(float f) {
  unsigned int u = __builtin_bit_cast(unsigned int, f);
  u += 0x7FFF + ((u >> 16) & 1);   // round-to-nearest-even
  return (unsigned short)(u >> 16);
}

// publish LDS writes; do NOT drain vmcnt (prefetch loads stay in flight)
__device__ __forceinline__ void bar_pub() {
  asm volatile("s_waitcnt lgkmcnt(0)" ::: "memory");
  __builtin_amdgcn_s_barrier();
  asm volatile("" ::: "memory");
}

// ---------------------------------------------------------------------------
// K1: QKV projection (unchanged).
// ---------------------------------------------------------------------------
__global__ __launch_bounds__(256) void qkv_kernel(
    const float* __restrict__ x, const float* __restrict__ Wq,
    const float* __restrict__ Wk, const float* __restrict__ Wv,
    const float* __restrict__ bq, const float* __restrict__ bk,
    const float* __restrict__ bv, unsigned short* __restrict__ qkv) {
  const int z = blockIdx.z;
  const float* W = (z == 0) ? Wq : (z == 1 ? Wk : Wv);
  const float* bias = (z == 0) ? bq : (z == 1 ? bk : bv);
  unsigned short* out = qkv + (size_t)z * BHn * Sn * Dn;

  __shared__ unsigned short As[128][40];
  __shared__ unsigned short BsT[128][40];

  const int t = threadIdx.x;
  const int l = t & 63, w = t >> 6;
  const int wm = w >> 1, wn = w & 1;
  const int m0 = blockIdx.x * 128, n0 = blockIdx.y * 128;

  f32x4 acc[4][4] = {};

  for (int k0 = 0; k0 < En; k0 += 32) {
    __syncthreads();
#pragma unroll
    for (int i = 0; i < 4; ++i) {
      int idx = t + i * 256;
      int row = idx >> 3, c4 = (idx & 7) * 4;
      float4 v = *reinterpret_cast<const float4*>(&x[(size_t)(m0 + row) * En + k0 + c4]);
      ushort4 p;
      p.x = f2bf(v.x); p.y = f2bf(v.y); p.z = f2bf(v.z); p.w = f2bf(v.w);
      *reinterpret_cast<ushort4*>(&As[row][c4]) = p;
    }
#pragma unroll
    for (int i = 0; i < 4; ++i) {
      int idx = t + i * 256;
      int kk = idx >> 5, c4 = (idx & 31) * 4;
      float4 v = *reinterpret_cast<const float4*>(&W[(size_t)(k0 + kk) * En + n0 + c4]);
      BsT[c4 + 0][kk] = f2bf(v.x);
      BsT[c4 + 1][kk] = f2bf(v.y);
      BsT[c4 + 2][kk] = f2bf(v.z);
      BsT[c4 + 3][kk] = f2bf(v.w);
    }
    __syncthreads();

    const int koff = (l >> 4) * 8;
    short8 a[4], bfr[4];
#pragma unroll
    for (int m = 0; m < 4; ++m)
      a[m] = *reinterpret_cast<const short8*>(&As[wm * 64 + m * 16 + (l & 15)][koff]);
#pragma unroll
    for (int n = 0; n < 4; ++n)
      bfr[n] = *reinterpret_cast<const short8*>(&BsT[wn * 64 + n * 16 + (l & 15)][koff]);
#pragma unroll
    for (int m = 0; m < 4; ++m)
#pragma unroll
      for (int n = 0; n < 4; ++n)
        acc[m][n] = __builtin_amdgcn_mfma_f32_16x16x32_bf16(a[m], bfr[n], acc[m][n], 0, 0, 0);
  }

#pragma unroll
  for (int m = 0; m < 4; ++m)
#pragma unroll
    for (int n = 0; n < 4; ++n)
#pragma unroll
      for (int j = 0; j < 4; ++j) {
        int row = m0 + wm * 64 + m * 16 + (l >> 4) * 4 + j;
        int col = n0 + wn * 64 + n * 16 + (l & 15);
        int s = row & (Sn - 1);
        float v = acc[m][n][j] + bias[s];
        int b = row >> 11;
        int h = col >> 7, d = col & 127;
        out[(size_t)((b * Hn + h) * Sn + s) * Dn + d] = f2bf(v);
      }
}

// ---------------------------------------------------------------------------
// K1b: V transpose  v[bh][s][d] -> vT[bh][d][s] (unchanged).
// ---------------------------------------------------------------------------
__global__ __launch_bounds__(256) void vtrans_kernel(
    const unsigned short* __restrict__ v, unsigned short* __restrict__ vT) {
  const int s0 = blockIdx.x * 64, d0 = blockIdx.y * 64;
  const int bh = blockIdx.z;
  const unsigned short* vp = v + (size_t)bh * Sn * Dn;
  unsigned short* op = vT + (size_t)bh * Dn * Sn;
  __shared__ unsigned short Ls[64][72];
  const int t = threadIdx.x;
#pragma unroll
  for (int it = 0; it < 2; ++it) {
    int flat = t + it * 256;
    int r = flat >> 3, cc = flat & 7;
    *reinterpret_cast<short8*>(&Ls[r][cc * 8]) =
        *reinterpret_cast<const short8*>(&vp[(size_t)(s0 + r) * Dn + d0 + cc * 8]);
  }
  __syncthreads();
#pragma unroll
  for (int it = 0; it < 2; ++it) {
    int flat = t + it * 256;
    int d = flat >> 3, sc = flat & 7;
    short8 o;
#pragma unroll
    for (int jo = 0; jo < 8; ++jo) {
      int jj = (jo + sc) & 7;
      o[jj] = (short)Ls[sc * 8 + jj][d];
    }
    *reinterpret_cast<short8*>(&op[(size_t)(d0 + d) * Sn + s0 + sc * 8]) = o;
  }
}

// ---------------------------------------------------------------------------
// K2: fused attention v3.  Block = 64 q-rows of one (b,h); 4 waves.
// NEW partition: wave w owns q-rows s0+w*16..+15 and ALL 64 cols of each
// K-tile (aq 64->16 VGPR; row-reduce is a pure in-wave butterfly).
// Wepi prefetched one tile ahead into registers (wr[4][4]).
// ---------------------------------------------------------------------------
__global__ __launch_bounds__(256, 2) void fused_attn3_kernel(
    const unsigned short* __restrict__ qkv, const unsigned short* __restrict__ vT,
    const float* __restrict__ Wepi, const float* __restrict__ bo,
    float* __restrict__ attn, float* __restrict__ effect) {
  const int bh = blockIdx.y;
  const int s0 = blockIdx.x * 64;
  const unsigned short* qp = qkv + (size_t)bh * Sn * Dn;
  const unsigned short* kp = qkv + (size_t)(BHn + bh) * Sn * Dn;
  const unsigned short* vt = vT + (size_t)bh * Dn * Sn;

  __shared__ unsigned short Kb[2][64 * 128];   // K tiles, XOR-swizzled chunks
  __shared__ unsigned short Vt[128 * 64];      // V^T tile [d][t], swizzled
  __shared__ unsigned short Ps[64 * 64];       // P tile bf16, swizzled

  const int t = threadIdx.x, l = t & 63, w = t >> 6;
  const int g = l >> 4, i = l & 15;
  const float scale = 0.022097086912079608f;  // 1/sqrt(2048)

  // A-frags: rows s0 + w*16 + i, 16 VGPR total
  short8 aq[4];
#pragma unroll
  for (int ks = 0; ks < 4; ++ks)
    aq[ks] = *reinterpret_cast<const short8*>(
        &qp[(size_t)(s0 + w * 16 + i) * Dn + ks * 32 + g * 8]);

  // staging descriptors
  int ksrc[4], kdst[4], vsrc[4], vdst[4];
#pragma unroll
  for (int it = 0; it < 4; ++it) {
    int flat = t + it * 256;
    int r = flat >> 4, cc = flat & 15;           // K tile: 64 rows x 16 chunks
    ksrc[it] = r * Dn + cc * 8;
    kdst[it] = r * 128 + ((cc ^ (r & 15)) << 3);
    int d = flat >> 3, ct = flat & 7;            // Vt tile: 128 rows x 8 chunks
    vsrc[it] = d * Sn + ct * 8;
    vdst[it] = d * 64 + ((ct ^ (d & 7)) << 3);
  }

  // ---------------- sweep 1: exp row-sums ----------------
  short8 kreg[4];
#pragma unroll
  for (int it = 0; it < 4; ++it)
    kreg[it] = *reinterpret_cast<const short8*>(&kp[ksrc[it]]);
#pragma unroll
  for (int it = 0; it < 4; ++it)
    *reinterpret_cast<short8*>(&Kb[0][kdst[it]]) = kreg[it];
#pragma unroll
  for (int it = 0; it < 4; ++it)
    kreg[it] = *reinterpret_cast<const short8*>(&kp[(size_t)64 * Dn + ksrc[it]]);
  bar_pub();

  float rs[4] = {0.f, 0.f, 0.f, 0.f};

  for (int kt = 0; kt < 32; ++kt) {
    const int b = kt & 1;
    f32x4 acc[4] = {};
    __builtin_amdgcn_s_setprio(1);
#pragma unroll
    for (int ks = 0; ks < 4; ++ks)
#pragma unroll
      for (int nf = 0; nf < 4; ++nf) {
        short8 bk = *reinterpret_cast<const short8*>(
            &Kb[b][(nf * 16 + i) * 128 + (((ks * 4 + g) ^ i) << 3)]);
        acc[nf] = __builtin_amdgcn_mfma_f32_16x16x32_bf16(aq[ks], bk, acc[nf], 0, 0, 0);
      }
    __builtin_amdgcn_s_setprio(0);
#pragma unroll
    for (int j = 0; j < 4; ++j)
      rs[j] += __expf(acc[0][j] * scale) + __expf(acc[1][j] * scale) +
               __expf(acc[2][j] * scale) + __expf(acc[3][j] * scale);
    if (kt < 31) {
#pragma unroll
      for (int it = 0; it < 4; ++it)
        *reinterpret_cast<short8*>(&Kb[b ^ 1][kdst[it]]) = kreg[it];
      if (kt < 30)
#pragma unroll
        for (int it = 0; it < 4; ++it)
          kreg[it] = *reinterpret_cast<const short8*>(
              &kp[(size_t)(kt + 2) * 64 * Dn + ksrc[it]]);
    }
    bar_pub();
  }

  // in-wave butterfly over the 16 i-lanes: every lane gets its row's sum
  float rinv[4];
#pragma unroll
  for (int j = 0; j < 4; ++j) {
    float s = rs[j];
    s += __shfl_xor(s, 1); s += __shfl_xor(s, 2);
    s += __shfl_xor(s, 4); s += __shfl_xor(s, 8);
    rinv[j] = 1.0f / s;
  }

  // ---------------- sweep 2: recompute, write attn, PV ----------------
  short8 vreg[4];
#pragma unroll
  for (int it = 0; it < 4; ++it) {
    kreg[it] = *reinterpret_cast<const short8*>(&kp[ksrc[it]]);
    vreg[it] = *reinterpret_cast<const short8*>(&vt[vsrc[it]]);
  }
#pragma unroll
  for (int it = 0; it < 4; ++it) {
    *reinterpret_cast<short8*>(&Kb[0][kdst[it]]) = kreg[it];
    *reinterpret_cast<short8*>(&Vt[vdst[it]]) = vreg[it];
  }
#pragma unroll
  for (int it = 0; it < 4; ++it) {
    kreg[it] = *reinterpret_cast<const short8*>(&kp[(size_t)64 * Dn + ksrc[it]]);
    vreg[it] = *reinterpret_cast<const short8*>(&vt[64 + vsrc[it]]);
  }
  // Wepi prefetch for kt=0 (row = s0+w*16+g*4+j, col = nf*16+i)
  const float* wbase = Wepi + (size_t)(s0 + w * 16 + g * 4) * Sn + i;
  float wr[4][4];
#pragma unroll
  for (int nf = 0; nf < 4; ++nf)
#pragma unroll
    for (int j = 0; j < 4; ++j)
      wr[nf][j] = wbase[(size_t)j * Sn + nf * 16];
  bar_pub();

  f32x4 pv[8] = {};
  float* attn_bh = attn + (size_t)bh * Sn * Sn;

  for (int kt = 0; kt < 32; ++kt) {
    const int b = kt & 1;
    const int t0 = kt * 64;
    f32x4 acc[4] = {};
    __builtin_amdgcn_s_setprio(1);
#pragma unroll
    for (int ks = 0; ks < 4; ++ks)
#pragma unroll
      for (int nf = 0; nf < 4; ++nf) {
        short8 bk = *reinterpret_cast<const short8*>(
            &Kb[b][(nf * 16 + i) * 128 + (((ks * 4 + g) ^ i) << 3)]);
        acc[nf] = __builtin_amdgcn_mfma_f32_16x16x32_bf16(aq[ks], bk, acc[nf], 0, 0, 0);
      }
    __builtin_amdgcn_s_setprio(0);

    // epilogue: p = exp*rinv*wr -> attn f32 (only global write) + Ps bf16
#pragma unroll
    for (int nf = 0; nf < 4; ++nf)
#pragma unroll
      for (int j = 0; j < 4; ++j) {
        const int row = w * 16 + g * 4 + j;
        const int col = nf * 16 + i;
        float pf = __expf(acc[nf][j] * scale) * rinv[j] * wr[nf][j];
        attn_bh[(size_t)(s0 + row) * Sn + t0 + col] = pf;
        Ps[row * 64 + ((((nf * 2 + (i >> 3)) ^ (row & 7)) << 3) | (i & 7))] = f2bf(pf);
      }
    // reload Wepi for kt+1 (covered by PV + next QK^T)
    if (kt < 31)
#pragma unroll
      for (int nf = 0; nf < 4; ++nf)
#pragma unroll
        for (int j = 0; j < 4; ++j)
          wr[nf][j] = wbase[(size_t)j * Sn + t0 + 64 + nf * 16];
    if (kt < 31)
#pragma unroll
      for (int it = 0; it < 4; ++it)
        *reinterpret_cast<short8*>(&Kb[b ^ 1][kdst[it]]) = kreg[it];
    bar_pub();   // Ps + next-K visible

    // PV: Ps [64s x 64t] x Vt [128d x 64t], wave w -> its 16 rows, all 128 d
    __builtin_amdgcn_s_setprio(1);
#pragma unroll
    for (int ks2 = 0; ks2 < 2; ++ks2) {
      short8 pa = *reinterpret_cast<const short8*>(
          &Ps[(w * 16 + i) * 64 + (((ks2 * 4 + g) ^ (i & 7)) << 3)]);
#pragma unroll
      for (int nf2 = 0; nf2 < 8; ++nf2) {
        const int d = nf2 * 16 + i;
        short8 bv = *reinterpret_cast<const short8*>(
            &Vt[d * 64 + (((ks2 * 4 + g) ^ (i & 7)) << 3)]);
        pv[nf2] = __builtin_amdgcn_mfma_f32_16x16x32_bf16(pa, bv, pv[nf2], 0, 0, 0);
      }
    }
    __builtin_amdgcn_s_setprio(0);
    bar_pub();   // Ps/Vt reads done

    if (kt < 31) {
#pragma unroll
      for (int it = 0; it < 4; ++it)
        *reinterpret_cast<short8*>(&Vt[vdst[it]]) = vreg[it];
      if (kt < 30)
#pragma unroll
        for (int it = 0; it < 4; ++it) {
          kreg[it] = *reinterpret_cast<const short8*>(
              &kp[(size_t)(t0 + 128) * Dn + ksrc[it]]);
          vreg[it] = *reinterpret_cast<const short8*>(&vt[t0 + 128 + vsrc[it]]);
        }
    }
  }

  // effect = pv + bo
  const int b_ = bh >> 2, h_ = bh & 3;
#pragma unroll
  for (int j = 0; j < 4; ++j) {
    const int row = s0 + w * 16 + g * 4 + j;
    const float bias = bo[row];
#pragma unroll
    for (int nf2 = 0; nf2 < 8; ++nf2)
      effect[(size_t)(b_ * Sn + row) * En + h_ * Dn + nf2 * 16 + i] = pv[nf2][j] + bias;
  }
}

// ---------------------------------------------------------------------------
extern "C" void kernel_launch(void* const* d_in, const int* in_sizes, int n_in,
                              void* d_out, int out_size, void* d_ws, size_t ws_size,
                              hipStream_t stream) {
  const float* x    = (const float*)d_in[0];
  const float* Wq   = (const float*)d_in[1];
  const float* Wk   = (const float*)d_in[2];
  const float* Wv   = (const float*)d_in[3];
  const float* Wepi = (const float*)d_in[4];
  const float* bq   = (const float*)d_in[5];
  const float* bk   = (const float*)d_in[6];
  const float* bv   = (const float*)d_in[7];
  const float* bo   = (const float*)d_in[8];

  float* effect = (float*)d_out;
  float* attn = effect + (size_t)Bn * Sn * En;              // attn region of d_out
  unsigned short* qkv = (unsigned short*)d_ws;              // q|k|v bf16 (50.3 MB)
  unsigned short* vT = qkv + (size_t)3 * BHn * Sn * Dn;     // v^T bf16 (16.8 MB)

  qkv_kernel<<<dim3(Mqkv / 128, En / 128, 3), 256, 0, stream>>>(x, Wq, Wk, Wv, bq, bk, bv, qkv);
  vtrans_kernel<<<dim3(Sn / 64, Dn / 64, BHn), 256, 0, stream>>>(
      qkv + (size_t)2 * BHn * Sn * Dn, vT);
  fused_attn3_kernel<<<dim3(Sn / 64, BHn), 256, 0, stream>>>(qkv, vT, Wepi, bo, attn, effect);
}